// Round 6
// baseline (129210.706 us; speedup 1.0000x reference)
//
#include <hip/hip_runtime.h>
#include <stdint.h>

// LSTM, 2 layers, T=2048 B=32 I=H=256. Dtype-adaptive (bf16 or fp32 inputs).
// Compute is bf16-MFMA with fp32 state either way.
//
// Persistent kernel, 32 worker WGs (16/layer). XCD-clustered execution:
// 256 blocks launched (1/CU); the 32 blocks on one XCD become workers so all
// h-exchange stays in that XCD's coherent L2 (sc0 ops) instead of crossing
// the inter-XCD fabric at agent scope (~3us RTT; 10.9us/step measured with
// ~0.6us work).
//
// R4 post-mortem: clustered run gave absmax 0.70 (stale h). Root causes
// covered now:
//  (C) cross-launch stale DIRTY L2 lines (warm-up launches leave sc0-dirty
//      flag/h_ex lines; memset via SDMA doesn't purge them; old flag values
//      >= tag let consumers race ahead)  -> fixed by EPOCH-TAGGED flags
//      (value = epoch<<16 | step, epoch from s_memrealtime, exact-epoch
//      compare; no dependence on initial memory state) + clustered mode uses
//      a DISJOINT ws region never touched by sc1 ops.
//  (A) sc0 load possibly not bypassing L1 on repeated addresses -> two-round
//      canary on one isolated line with launch-unique values; round 2
//      re-reads the SAME address expecting a NEW value. Any anomaly ->
//      unanimous demote to the verified agent-scope (sc1) fallback.
// Poison valves keep worst-case wall time ~1s on protocol failure.

#define TT 2048
#define BB 32
#define HH 256
#define NG 16            // workgroups per layer
#define UPW 16           // hidden units per WG
#define ROWS 64          // 4 gates * UPW weight rows per WG
#define KP 520           // padded K row length in bf16 elems (512 + 8)
#define NSLOT 2          // h-exchange ring depth
#define NBLK 256         // launched blocks (1 per CU); 32 become workers

#define OFF_W    0                       // [ROWS][KP] bf16  = 66560 B
#define OFF_HX   66560                   // [BB][KP]  bf16   = 33280 B
#define OFF_G    99840                   // [ROWS][33] f32   =  8448 B
#define OFF_HOB  108288                  // [BB][UPW] bf16   =  1024 B
#define OFF_COB  109312                  // [BB][UPW] bf16   =  1024 B
#define OFF_HOF  110336                  // [BB][UPW] f32    =  2048 B
#define OFF_COF  112384                  // [BB][UPW] f32    =  2048 B
#define OFF_DEAD 114432                  // int: block-wide poll-timeout poison
#define LDS_BYTES 114496

#define WS_HEX_DW    (2 * NSLOT * BB * (HH / 2))  // 16384 dwords = 64 KiB
#define WS_HEXF_OFF  0                            // fallback h_ex (sc1 only)
#define WS_FLAGF_OFF (WS_HEX_DW * 4)              // 65536: fallback flags
#define WS_FLAG_BYTES (2 * NSLOT * NG * 4)        // 256 B
#define WS_REG_OFF   (WS_FLAGF_OFF + WS_FLAG_BYTES)   // 65792: ClusterReg (agent ops)
#define WS_REG_BYTES 128
#define WS_CAN_OFF   66048                        // isolated 128B line: sc0 canary
#define WS_HEXC_OFF  66176                        // clustered h_ex (sc0 only)
#define WS_FLAGC_OFF (WS_HEXC_OFF + WS_HEX_DW * 4)    // 131712: clustered flags

typedef __attribute__((ext_vector_type(8))) short bf16x8;
typedef __attribute__((ext_vector_type(4))) float f32x4;
typedef unsigned short u16;
typedef unsigned int u32;

struct ClusterReg {
    int arrival;        // global arrival counter
    int xcd_cnt[16];    // per-XCD registration counts
    int decision;       // target xcd, or -1 = fallback
    int ready;          // decision+epoch published
    u32 epoch;          // launch-unique 15-bit epoch
    int ready2;         // canary K1 written
    u32 votes1;         // hi16 total, lo16 yes (canary round 1)
    u32 votes2;         // round 2
    int verdict;        // bit1 = published, bit0 = clustered ok
};

__device__ __forceinline__ float bf2f(u16 u) {
    u32 x = ((u32)u) << 16;
    return __builtin_bit_cast(float, x);
}
__device__ __forceinline__ u16 f2bf(float f) {
    u32 x = __builtin_bit_cast(u32, f);
    x += 0x7fffu + ((x >> 16) & 1u);   // RNE
    return (u16)(x >> 16);
}
__device__ __forceinline__ u32 pack2(float lo, float hi) {
    return (u32)f2bf(lo) | ((u32)f2bf(hi) << 16);
}
__device__ __forceinline__ float bcf(u32 v) { return __builtin_bit_cast(float, v); }
__device__ __forceinline__ uint4 cvt8(uint4 a, uint4 b) {
    uint4 r;
    r.x = pack2(bcf(a.x), bcf(a.y));
    r.y = pack2(bcf(a.z), bcf(a.w));
    r.z = pack2(bcf(b.x), bcf(b.y));
    r.w = pack2(bcf(b.z), bcf(b.w));
    return r;
}

// ---- agent-scope (cross-XCD, beyond-L2) coherent ops: fallback path ----
__device__ __forceinline__ u32 cload(const u32* p) {
    return __hip_atomic_load(p, __ATOMIC_RELAXED, __HIP_MEMORY_SCOPE_AGENT);
}
__device__ __forceinline__ void cstore(u32* p, u32 v) {
    __hip_atomic_store(p, v, __ATOMIC_RELAXED, __HIP_MEMORY_SCOPE_AGENT);
}
__device__ __forceinline__ int poll_ge(int* f, int tag) {       // 1 = timeout
    int it = 0;
    while (__hip_atomic_load(f, __ATOMIC_RELAXED, __HIP_MEMORY_SCOPE_AGENT) < tag) {
        __builtin_amdgcn_s_sleep(2);
        if (++it > 300000) return 1;
    }
    return 0;
}

// ---- XCD-local (shared-L2, sc0 = L1-bypass) ops: clustered path ----
__device__ __forceinline__ void st_sc0(u32* p, u32 v) {
    asm volatile("global_store_dword %0, %1, off sc0" :: "v"(p), "v"(v) : "memory");
}
__device__ __forceinline__ u32 ld_sc0_wait(const u32* p) {
    u32 v;
    asm volatile("global_load_dword %0, %1, off sc0\n\ts_waitcnt vmcnt(0)"
                 : "=v"(v) : "v"(p) : "memory");
    return v;
}
// exact-match poll (canary): 1 = timeout
__device__ __forceinline__ int poll_exact_loc(const u32* p, u32 want) {
    int it = 0;
    while (ld_sc0_wait(p) != want) {
        __builtin_amdgcn_s_sleep(1);
        if (++it > 1000000) return 1;
    }
    return 0;
}
// epoch-tagged >= poll (main loop): 1 = timeout
__device__ __forceinline__ int poll_flag_loc(int* f, u32 ep, int tag) {
    int it = 0;
    while (true) {
        u32 v = ld_sc0_wait((const u32*)f);
        if ((v >> 16) == ep && (int)(v & 0xffffu) >= tag) return 0;
        __builtin_amdgcn_s_sleep(1);
        if (++it > 1000000) return 1;
    }
}

__global__ __launch_bounds__(256) void lstm_kernel(
    const u16* __restrict__ x, const int* __restrict__ lengths,
    const u16* __restrict__ h0, const u16* __restrict__ c0,
    const u16* __restrict__ Wih0, const u16* __restrict__ Whh0, const u16* __restrict__ b0,
    const u16* __restrict__ Wih1, const u16* __restrict__ Whh1, const u16* __restrict__ b1,
    u16* __restrict__ out, u32* __restrict__ ws)
{
    extern __shared__ char lds[];
    const int tid = threadIdx.x;
    ClusterReg* rg = (ClusterReg*)((char*)ws + WS_REG_OFF);

    // ================= cluster formation + stale/coherence canary =================
    if (tid == 0) {
        int myxcd = __builtin_amdgcn_s_getreg(6164) & 15;  // HW_REG_XCC_ID(20), off0, sz4
        int myArr = atomicAdd(&rg->arrival, 1);
        int myIdx = atomicAdd(&rg->xcd_cnt[myxcd], 1);
        int dec;
        if (myArr == 0) {
            int it = 0;   // leader: wait for all 256 co-resident blocks
            while (__hip_atomic_load(&rg->arrival, __ATOMIC_RELAXED, __HIP_MEMORY_SCOPE_AGENT) < NBLK
                   && ++it < 100000) __builtin_amdgcn_s_sleep(2);
            int best = -1, bestc = 0;
            for (int i = 0; i < 16; ++i) {
                int c = __hip_atomic_load(&rg->xcd_cnt[i], __ATOMIC_RELAXED, __HIP_MEMORY_SCOPE_AGENT);
                if (c > bestc) { bestc = c; best = i; }
            }
            dec = (bestc >= 32 && bestc <= 48) ? best : -1;
            u32 ep0 = (u32)((__builtin_amdgcn_s_memrealtime() >> 15) & 0x7fffu);
            __hip_atomic_store(&rg->epoch, ep0, __ATOMIC_RELAXED, __HIP_MEMORY_SCOPE_AGENT);
            __hip_atomic_store(&rg->decision, dec, __ATOMIC_RELAXED, __HIP_MEMORY_SCOPE_AGENT);
            __hip_atomic_store(&rg->ready, 1, __ATOMIC_RELEASE, __HIP_MEMORY_SCOPE_AGENT);
        } else {
            int it = 0;
            while (__hip_atomic_load(&rg->ready, __ATOMIC_ACQUIRE, __HIP_MEMORY_SCOPE_AGENT) == 0
                   && ++it < 4000000) __builtin_amdgcn_s_sleep(2);
            dec = __hip_atomic_load(&rg->decision, __ATOMIC_RELAXED, __HIP_MEMORY_SCOPE_AGENT);
        }
        u32 ep0 = __hip_atomic_load(&rg->epoch, __ATOMIC_RELAXED, __HIP_MEMORY_SCOPE_AGENT);
        int role = -1, lcv = 0;
        if (dec >= 0) { if (myxcd == dec && myIdx < 32) { role = myIdx; lcv = 1; } }
        else if (myArr < 32) role = myArr;   // fallback: first 32 arrivals, sc1 path

        if (lcv) {
            // two-round canary on an isolated line, launch-unique values:
            // round1 = basic intra-cluster sc0 coherence (+ cross-launch stale
            // detection via launch-unique K1); round2 = REPEATED-ADDRESS
            // update visibility (catches L1-staleness on re-reads).
            u32* can = (u32*)((char*)ws + WS_CAN_OFF);
            const u32 K1 = (ep0 << 16) | 0x1A51u;
            const u32 K2 = (ep0 << 16) | 0xA515u;
            if (role == 0) {
                st_sc0(can, K1);
                asm volatile("s_waitcnt vmcnt(0)" ::: "memory");
                __hip_atomic_store(&rg->ready2, 1, __ATOMIC_RELEASE, __HIP_MEMORY_SCOPE_AGENT);
            }
            { int it = 0; while (__hip_atomic_load(&rg->ready2, __ATOMIC_ACQUIRE, __HIP_MEMORY_SCOPE_AGENT) == 0
                                 && ++it < 4000000) __builtin_amdgcn_s_sleep(2); }
            int ok1 = poll_exact_loc(can, K1);
            atomicAdd(&rg->votes1, ok1 ? 0x10000u : 0x10001u);
            if (role == 0) {
                int it = 0;
                while ((__hip_atomic_load(&rg->votes1, __ATOMIC_RELAXED, __HIP_MEMORY_SCOPE_AGENT) >> 16) < 32u
                       && ++it < 4000000) __builtin_amdgcn_s_sleep(2);
                st_sc0(can, K2);                       // SAME address, new value
                asm volatile("s_waitcnt vmcnt(0)" ::: "memory");
            }
            int ok2 = poll_exact_loc(can, K2);
            atomicAdd(&rg->votes2, ok2 ? 0x10000u : 0x10001u);
            if (role == 0) {
                int it = 0;
                while ((__hip_atomic_load(&rg->votes2, __ATOMIC_RELAXED, __HIP_MEMORY_SCOPE_AGENT) >> 16) < 32u
                       && ++it < 4000000) __builtin_amdgcn_s_sleep(2);
                u32 v1 = __hip_atomic_load(&rg->votes1, __ATOMIC_RELAXED, __HIP_MEMORY_SCOPE_AGENT);
                u32 v2 = __hip_atomic_load(&rg->votes2, __ATOMIC_RELAXED, __HIP_MEMORY_SCOPE_AGENT);
                int vd = (((v1 & 0xffffu) == 32u) && ((v2 & 0xffffu) == 32u)) ? 3 : 2;
                __hip_atomic_store(&rg->verdict, vd, __ATOMIC_RELEASE, __HIP_MEMORY_SCOPE_AGENT);
            }
            int vd = 0;
            { int it = 0; while ((((vd = __hip_atomic_load(&rg->verdict, __ATOMIC_ACQUIRE, __HIP_MEMORY_SCOPE_AGENT)) & 2) == 0)
                                 && ++it < 6000000) __builtin_amdgcn_s_sleep(2); }
            lcv = vd & 1;                              // single-writer verdict: all agree
        }
        ((volatile int*)lds)[0] = role;
        ((volatile int*)lds)[1] = lcv;
        ((volatile u32*)lds)[2] = ep0;
    }
    __syncthreads();
    const int wg = ((volatile int*)lds)[0];
    const int lc0 = ((volatile int*)lds)[1];
    const u32 ep = ((volatile u32*)lds)[2];
    __syncthreads();
    if (wg < 0) return;                          // 224 non-worker blocks exit
    const bool loc = (lc0 != 0);

    // region select: clustered region is ONLY ever touched by sc0 ops;
    // fallback region ONLY by sc1 ops (prevents stale-dirty-line crosstalk)
    u32* hx = (u32*)((char*)ws + (loc ? WS_HEXC_OFF : WS_HEXF_OFF));
    int* fl = (int*)((char*)ws + (loc ? WS_FLAGC_OFF : WS_FLAGF_OFF));

    const int layer = wg >> 4;
    const int g = wg & 15;
    const int ubase = g * UPW;

    // ---- dtype probe ----
    if (tid == 0) *(volatile int*)lds = 0;
    __syncthreads();
    {
        int e = (((const u16*)x)[(u32)tid * 64] >> 7) & 0xff;
        if (e >= 96 && e <= 144) atomicAdd((int*)lds, 1);
    }
    __syncthreads();
    const bool bfm = (*(volatile int*)lds >= 150);
    __syncthreads();

    const u16* Wih = layer ? Wih1 : Wih0;
    const u16* Whh = layer ? Whh1 : Whh0;
    const u16* bias = layer ? b1 : b0;

    // ---- load fused [W_ih | W_hh] slice into LDS ----
    if (tid == 0) *(volatile int*)(lds + OFF_DEAD) = 0;
    for (int c = tid; c < ROWS * 64; c += 256) {
        int r = c >> 6, part = c & 63;
        int R = (r & 3) * 256 + ubase + (r >> 2);    // gate*256 + unit
        uint4 v;
        if (bfm) {
            v = (part < 32) ? ((const uint4*)Wih)[R * 32 + part]
                            : ((const uint4*)Whh)[R * 32 + (part - 32)];
        } else {
            const uint4* s = (part < 32) ? ((const uint4*)Wih) + R * 64 + part * 2
                                         : ((const uint4*)Whh) + R * 64 + (part - 32) * 2;
            v = cvt8(s[0], s[1]);
        }
        *(uint4*)(lds + OFF_W + r * (KP * 2) + part * 16) = v;
    }

    // ---- per-thread recurrent state ----
    const int b = tid & 31;
    const int u0 = tid >> 5;            // 0..7
    const bool len64 = (lengths[1] == 0);
    const int lenb = len64 ? lengths[2 * b] : lengths[b];
    float cr[2], hp[2], bi[2][4];
#pragma unroll
    for (int pp = 0; pp < 2; ++pp) {
        int ug = ubase + u0 + 8 * pp;
        int idx = layer * BB * HH + b * HH + ug;
        cr[pp] = bfm ? bf2f(c0[idx]) : ((const float*)c0)[idx];
        hp[pp] = bfm ? bf2f(h0[idx]) : ((const float*)h0)[idx];
#pragma unroll
        for (int gate = 0; gate < 4; ++gate)
            bi[pp][gate] = bfm ? bf2f(bias[gate * 256 + ug])
                               : ((const float*)bias)[gate * 256 + ug];
    }

    // x prefetch (layer 0)
    uint4 xr[8];
    if (layer == 0) {
        if (bfm) {
#pragma unroll
            for (int j = 0; j < 4; ++j) xr[j] = ((const uint4*)x)[tid + j * 256];
        } else {
#pragma unroll
            for (int j = 0; j < 4; ++j) {
                int e = tid + j * 256;
                xr[2 * j]     = ((const uint4*)x)[2 * e];
                xr[2 * j + 1] = ((const uint4*)x)[2 * e + 1];
            }
        }
    }

    const int lane = tid & 63;
    const int wave = tid >> 6;
    const int lq = lane >> 4;
    const int lm = lane & 15;
    int blkdead = 0;     // block-wide poison: once set, never poll again

    __syncthreads();   // weights + dead flag visible

    for (int t = 0; t < TT; ++t) {
        const int slot = t & (NSLOT - 1);
        const int pslot = (t - 1) & (NSLOT - 1);

        // ---- producer waits (wave0) + ring back-pressure (wave1) ----
        if (!blkdead) {
            int to = 0;
            if (layer == 0) {
                if (wave == 0 && lane < 16 && t > 0) {
                    int* f = &fl[(0 * NSLOT + pslot) * NG + lane];
                    to = loc ? poll_flag_loc(f, ep, t) : poll_ge(f, t);
                }
                if (wave == 1 && lane < 16 && t >= NSLOT) {
                    int* f = &fl[(1 * NSLOT + slot) * NG + lane];
                    to = loc ? poll_flag_loc(f, ep, t - NSLOT + 1) : poll_ge(f, t - NSLOT + 1);
                }
            } else {
                if (wave == 0 && lane < 16) {
                    int* f = &fl[(0 * NSLOT + slot) * NG + lane];
                    to = loc ? poll_flag_loc(f, ep, t + 1) : poll_ge(f, t + 1);
                }
                if (wave == 1 && lane < 16 && t > 0) {
                    int* f = &fl[(1 * NSLOT + pslot) * NG + lane];
                    to = loc ? poll_flag_loc(f, ep, t) : poll_ge(f, t);
                }
            }
            if (to) atomicOr((int*)(lds + OFF_DEAD), 1);
        }
        asm volatile("" ::: "memory");
        __syncthreads();
        blkdead |= *(volatile int*)(lds + OFF_DEAD);

        // ---- stage hx_tile = [x_t or h0_t | h_prev] into LDS ----
        if (layer == 0) {
#pragma unroll
            for (int j = 0; j < 4; ++j) {
                int e = tid + j * 256;
                uint4 v = bfm ? xr[j] : cvt8(xr[2 * j], xr[2 * j + 1]);
                *(uint4*)(lds + OFF_HX + (e >> 5) * (KP * 2) + (e & 31) * 16) = v;
            }
            if (t == 0) {
#pragma unroll
                for (int j = 0; j < 16; ++j) {
                    int d = tid + j * 256;
                    u32 v = bfm ? ((const u32*)h0)[d]
                                : pack2(((const float*)h0)[2 * d], ((const float*)h0)[2 * d + 1]);
                    *(u32*)(lds + OFF_HX + (d >> 7) * (KP * 2) + 512 + (d & 127) * 4) = v;
                }
            } else {
                u32* src = hx + (0 * NSLOT + pslot) * (BB * 128);
                if (loc) {
                    u32 tmp[16];
#pragma unroll
                    for (int j = 0; j < 16; ++j)
                        asm volatile("global_load_dword %0, %1, off sc0"
                                     : "=v"(tmp[j]) : "v"(src + tid + j * 256));
                    asm volatile("s_waitcnt vmcnt(0)" ::: "memory");
                    __builtin_amdgcn_sched_barrier(0);
#pragma unroll
                    for (int j = 0; j < 16; ++j) {
                        int d = tid + j * 256;
                        *(u32*)(lds + OFF_HX + (d >> 7) * (KP * 2) + 512 + (d & 127) * 4) = tmp[j];
                    }
                } else {
#pragma unroll
                    for (int j = 0; j < 16; ++j) {
                        int d = tid + j * 256;
                        u32 v = cload(src + d);
                        *(u32*)(lds + OFF_HX + (d >> 7) * (KP * 2) + 512 + (d & 127) * 4) = v;
                    }
                }
            }
            if (t + 1 < TT) {
                if (bfm) {
#pragma unroll
                    for (int j = 0; j < 4; ++j)
                        xr[j] = ((const uint4*)x)[(t + 1) * 1024 + tid + j * 256];
                } else {
#pragma unroll
                    for (int j = 0; j < 4; ++j) {
                        int e = tid + j * 256;
                        xr[2 * j]     = ((const uint4*)x)[(t + 1) * 2048 + 2 * e];
                        xr[2 * j + 1] = ((const uint4*)x)[(t + 1) * 2048 + 2 * e + 1];
                    }
                }
            }
        } else {
            u32* src0 = hx + (0 * NSLOT + slot) * (BB * 128);
            if (loc) {
                u32 t0[16], t1[16];
#pragma unroll
                for (int j = 0; j < 16; ++j)
                    asm volatile("global_load_dword %0, %1, off sc0"
                                 : "=v"(t0[j]) : "v"(src0 + tid + j * 256));
                if (t > 0) {
                    u32* src1 = hx + (1 * NSLOT + pslot) * (BB * 128);
#pragma unroll
                    for (int j = 0; j < 16; ++j)
                        asm volatile("global_load_dword %0, %1, off sc0"
                                     : "=v"(t1[j]) : "v"(src1 + tid + j * 256));
                }
                asm volatile("s_waitcnt vmcnt(0)" ::: "memory");
                __builtin_amdgcn_sched_barrier(0);
#pragma unroll
                for (int j = 0; j < 16; ++j) {
                    int d = tid + j * 256;
                    *(u32*)(lds + OFF_HX + (d >> 7) * (KP * 2) + (d & 127) * 4) = t0[j];
                }
                if (t > 0) {
#pragma unroll
                    for (int j = 0; j < 16; ++j) {
                        int d = tid + j * 256;
                        *(u32*)(lds + OFF_HX + (d >> 7) * (KP * 2) + 512 + (d & 127) * 4) = t1[j];
                    }
                } else {
#pragma unroll
                    for (int j = 0; j < 16; ++j) {
                        int d = tid + j * 256;
                        u32 v = bfm ? ((const u32*)h0)[4096 + d]
                                    : pack2(((const float*)h0)[8192 + 2 * d],
                                            ((const float*)h0)[8192 + 2 * d + 1]);
                        *(u32*)(lds + OFF_HX + (d >> 7) * (KP * 2) + 512 + (d & 127) * 4) = v;
                    }
                }
            } else {
#pragma unroll
                for (int j = 0; j < 16; ++j) {
                    int d = tid + j * 256;
                    u32 v = cload(src0 + d);
                    *(u32*)(lds + OFF_HX + (d >> 7) * (KP * 2) + (d & 127) * 4) = v;
                }
                if (t == 0) {
#pragma unroll
                    for (int j = 0; j < 16; ++j) {
                        int d = tid + j * 256;
                        u32 v = bfm ? ((const u32*)h0)[4096 + d]
                                    : pack2(((const float*)h0)[8192 + 2 * d],
                                            ((const float*)h0)[8192 + 2 * d + 1]);
                        *(u32*)(lds + OFF_HX + (d >> 7) * (KP * 2) + 512 + (d & 127) * 4) = v;
                    }
                } else {
                    u32* src1 = hx + (1 * NSLOT + pslot) * (BB * 128);
#pragma unroll
                    for (int j = 0; j < 16; ++j) {
                        int d = tid + j * 256;
                        u32 v = cload(src1 + d);
                        *(u32*)(lds + OFF_HX + (d >> 7) * (KP * 2) + 512 + (d & 127) * 4) = v;
                    }
                }
            }
        }
        __syncthreads();

        // ---- MFMA: gates[batch 32][row 64] = hx[32,512] @ W[64,512]^T ----
        {
            f32x4 acc0 = {0.f, 0.f, 0.f, 0.f}, acc1 = {0.f, 0.f, 0.f, 0.f};
            const int n = wave * 16 + lm;
            const char* wrow  = lds + OFF_W  + n * (KP * 2) + lq * 16;
            const char* arow0 = lds + OFF_HX + lm * (KP * 2) + lq * 16;
            const char* arow1 = lds + OFF_HX + (16 + lm) * (KP * 2) + lq * 16;
#pragma unroll
            for (int ks = 0; ks < 16; ++ks) {
                bf16x8 bf = *(const bf16x8*)(wrow + ks * 64);
                bf16x8 a0 = *(const bf16x8*)(arow0 + ks * 64);
                bf16x8 a1 = *(const bf16x8*)(arow1 + ks * 64);
                acc0 = __builtin_amdgcn_mfma_f32_16x16x32_bf16(a0, bf, acc0, 0, 0, 0);
                acc1 = __builtin_amdgcn_mfma_f32_16x16x32_bf16(a1, bf, acc1, 0, 0, 0);
            }
            float* gcol = (float*)(lds + OFF_G) + n * 33;   // gates[row][batch]
#pragma unroll
            for (int r = 0; r < 4; ++r) {
                gcol[lq * 4 + r]      = acc0[r];
                gcol[16 + lq * 4 + r] = acc1[r];
            }
        }
        __syncthreads();

        // ---- pointwise LSTM cell update (fp32) ----
        {
            const float* gb = (const float*)(lds + OFF_G);
            u16* hob = (u16*)(lds + OFF_HOB);
            u16* cob = (u16*)(lds + OFF_COB);
#pragma unroll
            for (int pp = 0; pp < 2; ++pp) {
                int u = u0 + 8 * pp;
                float gi = gb[(4 * u + 0) * 33 + b] + bi[pp][0];
                float gf = gb[(4 * u + 1) * 33 + b] + bi[pp][1];
                float gg = gb[(4 * u + 2) * 33 + b] + bi[pp][2];
                float go = gb[(4 * u + 3) * 33 + b] + bi[pp][3];
                float si = 1.f / (1.f + __expf(-gi));
                float sf = 1.f / (1.f + __expf(-gf));
                float so = 1.f / (1.f + __expf(-go));
                float cn = sf * cr[pp] + si * tanhf(gg);
                float hn = so * tanhf(cn);
                if (t >= lenb) { cn = cr[pp]; hn = hp[pp]; }
                cr[pp] = cn; hp[pp] = hn;
                hob[b * UPW + u] = f2bf(hn);
                cob[b * UPW + u] = f2bf(cn);
                if (!bfm) {
                    ((float*)(lds + OFF_HOF))[b * UPW + u] = hn;
                    ((float*)(lds + OFF_COF))[b * UPW + u] = cn;
                }
            }
        }
        __syncthreads();

        // ---- publish h slice; flag; THEN layer-1 hs/cs output writes ----
        const u32 hv = ((const u32*)(lds + OFF_HOB))[tid];
        const int bb2 = tid >> 3, u2 = tid & 7;
        {
            u32* dst = hx + (layer * NSLOT + slot) * (BB * 128) + bb2 * 128 + g * 8 + u2;
            if (loc) st_sc0(dst, hv); else cstore(dst, hv);
        }
        asm volatile("s_waitcnt vmcnt(0)" ::: "memory");
        __syncthreads();
        if (tid == 0) {
            int* f = &fl[(layer * NSLOT + slot) * NG + g];
            if (loc) st_sc0((u32*)f, (ep << 16) | (u32)(t + 1));
            else __hip_atomic_store(f, t + 1, __ATOMIC_RELAXED, __HIP_MEMORY_SCOPE_AGENT);
        }
        if (layer == 1) {
            if (bfm) {
                u32 cv = ((const u32*)(lds + OFF_COB))[tid];
                u32* outu = (u32*)out;
                outu[t * 4096 + bb2 * 128 + g * 8 + u2] = hv;
                outu[(TT * BB * HH / 2) + t * 4096 + bb2 * 128 + g * 8 + u2] = cv;
            } else {
                float2 h2 = ((const float2*)(lds + OFF_HOF))[tid];
                float2 c2 = ((const float2*)(lds + OFF_COF))[tid];
                float2* outf2 = (float2*)out;
                outf2[t * 4096 + bb2 * 128 + g * 8 + u2] = h2;
                outf2[(TT * BB * HH / 2) + t * 4096 + bb2 * 128 + g * 8 + u2] = c2;
            }
        }
        __syncthreads();
    }

    // ---- finals: h_T, c_T (post-mask, held in regs) ----
    {
        const int base = 2 * TT * BB * HH;
#pragma unroll
        for (int pp = 0; pp < 2; ++pp) {
            int ug = ubase + u0 + 8 * pp;
            if (bfm) {
                out[base + layer * BB * HH + b * HH + ug] = f2bf(hp[pp]);
                out[base + 2 * BB * HH + layer * BB * HH + b * HH + ug] = f2bf(cr[pp]);
            } else {
                float* outf = (float*)out;
                outf[base + layer * BB * HH + b * HH + ug] = hp[pp];
                outf[base + 2 * BB * HH + layer * BB * HH + b * HH + ug] = cr[pp];
            }
        }
    }
}

extern "C" void kernel_launch(void* const* d_in, const int* in_sizes, int n_in,
                              void* d_out, int out_size, void* d_ws, size_t ws_size,
                              hipStream_t stream) {
    (void)in_sizes; (void)n_in; (void)out_size; (void)ws_size;
    // Deterministic init of FALLBACK region + ClusterReg only. The clustered
    // region needs NO init: epoch-tagged exact-match flags make any initial
    // (or stale) memory content a non-match, and h_ex reads are gated by
    // this launch's flags.
    hipMemsetAsync(d_ws, 0, WS_FLAGF_OFF, stream);
    hipMemsetAsync((char*)d_ws + WS_FLAGF_OFF, 0xFF, WS_FLAG_BYTES, stream);
    hipMemsetAsync((char*)d_ws + WS_REG_OFF, 0, WS_REG_BYTES, stream);
    hipFuncSetAttribute((const void*)lstm_kernel,
                        hipFuncAttributeMaxDynamicSharedMemorySize, LDS_BYTES);
    lstm_kernel<<<dim3(NBLK), dim3(256), LDS_BYTES, stream>>>(
        (const u16*)d_in[0], (const int*)d_in[1],
        (const u16*)d_in[2], (const u16*)d_in[3],
        (const u16*)d_in[4], (const u16*)d_in[5], (const u16*)d_in[6],
        (const u16*)d_in[7], (const u16*)d_in[8], (const u16*)d_in[9],
        (u16*)d_out, (u32*)d_ws);
}

// Round 9
// 32693.625 us; speedup vs baseline: 3.9522x; 3.9522x over previous
//
#include <hip/hip_runtime.h>
#include <stdint.h>

// LSTM, 2 layers, T=2048 B=32 I=H=256. Dtype-adaptive (bf16 or fp32 inputs).
// Compute is bf16-MFMA with fp32 state either way.
//
// Persistent kernel, 32 worker WGs (16/layer). XCD-clustered execution:
// 256 blocks launched (1/CU); the 32 blocks on one XCD become workers so all
// h-exchange stays in that XCD's L2.
//
// R6 post-mortem (measured): cluster formed (FETCH 531->75MB), correctness
// passed (epoch flags), but 63us/step: sc0 loads do NOT bypass the per-CU L1
// on repeated reads -- polls spun until chance L1 eviction. R4's fast+wrong
// run is the same mechanism (stale >=tag flag lines served from cache).
// Fix: consumer-side L1 invalidation via the COMPILER's agent acquire fence
// (__builtin_amdgcn_fence(__ATOMIC_ACQUIRE,"agent"), valid gfx950 codegen):
//  - poll loop: plain reload -> check -> fence -> sleep (each retry refetches
//    from the shared local L2 where the producer's sc0 stores commit)
//  - data: one fence, then plain uint4 loads (local-L2 hits, vectorized)
//  - two-round canary now exercises EXACTLY this mechanism with tight
//    budgets; any slow/stale verdict demotes to the verified sc1 fallback.
// Poison valves keep worst-case wall time bounded on protocol failure.

#define TT 2048
#define BB 32
#define HH 256
#define NG 16            // workgroups per layer
#define UPW 16           // hidden units per WG
#define ROWS 64          // 4 gates * UPW weight rows per WG
#define KP 520           // padded K row length in bf16 elems (512 + 8)
#define NSLOT 2          // h-exchange ring depth
#define NBLK 256         // launched blocks (1 per CU); 32 become workers

#define OFF_W    0                       // [ROWS][KP] bf16  = 66560 B
#define OFF_HX   66560                   // [BB][KP]  bf16   = 33280 B
#define OFF_G    99840                   // [ROWS][33] f32   =  8448 B
#define OFF_HOB  108288                  // [BB][UPW] bf16   =  1024 B
#define OFF_COB  109312                  // [BB][UPW] bf16   =  1024 B
#define OFF_HOF  110336                  // [BB][UPW] f32    =  2048 B
#define OFF_COF  112384                  // [BB][UPW] f32    =  2048 B
#define OFF_DEAD 114432                  // int: block-wide poll-timeout poison
#define LDS_BYTES 114496

#define WS_HEX_DW    (2 * NSLOT * BB * (HH / 2))  // 16384 dwords = 64 KiB
#define WS_HEXF_OFF  0                            // fallback h_ex (sc1 only)
#define WS_FLAGF_OFF (WS_HEX_DW * 4)              // 65536: fallback flags
#define WS_FLAG_BYTES (2 * NSLOT * NG * 4)        // 256 B
#define WS_REG_OFF   (WS_FLAGF_OFF + WS_FLAG_BYTES)   // 65792: ClusterReg (agent ops)
#define WS_REG_BYTES 128
#define WS_CAN_OFF   66048                        // isolated 128B line: sc0 canary
#define WS_HEXC_OFF  66176                        // clustered h_ex (sc0 only)
#define WS_FLAGC_OFF (WS_HEXC_OFF + WS_HEX_DW * 4)    // 131712: clustered flags

typedef __attribute__((ext_vector_type(8))) short bf16x8;
typedef __attribute__((ext_vector_type(4))) float f32x4;
typedef unsigned short u16;
typedef unsigned int u32;

struct ClusterReg {
    int arrival;        // global arrival counter
    int xcd_cnt[16];    // per-XCD registration counts
    int decision;       // target xcd, or -1 = fallback
    int ready;          // decision+epoch published
    u32 epoch;          // launch-unique 15-bit epoch
    int ready2;         // canary K1 written
    u32 votes1;         // hi16 total, lo16 yes (canary round 1)
    u32 votes2;         // round 2
    int verdict;        // bit1 = published, bit0 = clustered ok
};

__device__ __forceinline__ float bf2f(u16 u) {
    u32 x = ((u32)u) << 16;
    return __builtin_bit_cast(float, x);
}
__device__ __forceinline__ u16 f2bf(float f) {
    u32 x = __builtin_bit_cast(u32, f);
    x += 0x7fffu + ((x >> 16) & 1u);   // RNE
    return (u16)(x >> 16);
}
__device__ __forceinline__ u32 pack2(float lo, float hi) {
    return (u32)f2bf(lo) | ((u32)f2bf(hi) << 16);
}
__device__ __forceinline__ float bcf(u32 v) { return __builtin_bit_cast(float, v); }
__device__ __forceinline__ uint4 cvt8(uint4 a, uint4 b) {
    uint4 r;
    r.x = pack2(bcf(a.x), bcf(a.y));
    r.y = pack2(bcf(a.z), bcf(a.w));
    r.z = pack2(bcf(b.x), bcf(b.y));
    r.w = pack2(bcf(b.z), bcf(b.w));
    return r;
}

// ---- agent-scope (cross-XCD) coherent ops: fallback path ----
__device__ __forceinline__ u32 cload(const u32* p) {
    return __hip_atomic_load(p, __ATOMIC_RELAXED, __HIP_MEMORY_SCOPE_AGENT);
}
__device__ __forceinline__ void cstore(u32* p, u32 v) {
    __hip_atomic_store(p, v, __ATOMIC_RELAXED, __HIP_MEMORY_SCOPE_AGENT);
}
__device__ __forceinline__ int poll_ge(int* f, int tag) {       // 1 = timeout
    int it = 0;
    while (__hip_atomic_load(f, __ATOMIC_RELAXED, __HIP_MEMORY_SCOPE_AGENT) < tag) {
        __builtin_amdgcn_s_sleep(2);
        if (++it > 300000) return 1;
    }
    return 0;
}

// ---- XCD-local (shared-L2) ops: clustered path ----
// stores: sc0 (L1-bypass/write-through, commit to local L2 -- R6-proven)
__device__ __forceinline__ void st_sc0(u32* p, u32 v) {
    asm volatile("global_store_dword %0, %1, off sc0" :: "v"(p), "v"(v) : "memory");
}
// loads: plain load + COMPILER agent-acquire fence (invalidates L1 so the
// next load refetches from L2; sc0 loads alone are L1-sticky -- R6 measured)
__device__ __forceinline__ u32 ld_wg(const u32* p) {
    return __hip_atomic_load(p, __ATOMIC_RELAXED, __HIP_MEMORY_SCOPE_WORKGROUP);
}
__device__ __forceinline__ void inv_acq() {
    __builtin_amdgcn_fence(__ATOMIC_ACQUIRE, "agent");
}
// exact-match poll (canary): 1 = timeout. Mechanism-matched to data reads.
__device__ __forceinline__ int poll_exact_loc(const u32* p, u32 want) {
    int it = 0;
    while (true) {
        u32 v = ld_wg(p);
        if (v == want) { inv_acq(); return 0; }
        inv_acq();
        __builtin_amdgcn_s_sleep(1);
        if (++it > 200000) return 1;
    }
}
// epoch-tagged >= poll (main loop): 1 = timeout
__device__ __forceinline__ int poll_flag_loc(int* f, u32 ep, int tag) {
    int it = 0;
    while (true) {
        u32 v = ld_wg((const u32*)f);
        if ((v >> 16) == ep && (int)(v & 0xffffu) >= tag) { inv_acq(); return 0; }
        inv_acq();
        __builtin_amdgcn_s_sleep(1);
        if (++it > 500000) return 1;
    }
}

__global__ __launch_bounds__(256) void lstm_kernel(
    const u16* __restrict__ x, const int* __restrict__ lengths,
    const u16* __restrict__ h0, const u16* __restrict__ c0,
    const u16* __restrict__ Wih0, const u16* __restrict__ Whh0, const u16* __restrict__ b0,
    const u16* __restrict__ Wih1, const u16* __restrict__ Whh1, const u16* __restrict__ b1,
    u16* __restrict__ out, u32* __restrict__ ws)
{
    extern __shared__ char lds[];
    const int tid = threadIdx.x;
    ClusterReg* rg = (ClusterReg*)((char*)ws + WS_REG_OFF);

    // ================= cluster formation + mechanism canary =================
    if (tid == 0) {
        int myxcd = __builtin_amdgcn_s_getreg(6164) & 15;  // HW_REG_XCC_ID(20), off0, sz4
        int myArr = atomicAdd(&rg->arrival, 1);
        int myIdx = atomicAdd(&rg->xcd_cnt[myxcd], 1);
        int dec;
        if (myArr == 0) {
            int it = 0;   // leader: wait for all 256 co-resident blocks
            while (__hip_atomic_load(&rg->arrival, __ATOMIC_RELAXED, __HIP_MEMORY_SCOPE_AGENT) < NBLK
                   && ++it < 100000) __builtin_amdgcn_s_sleep(2);
            int best = -1, bestc = 0;
            for (int i = 0; i < 16; ++i) {
                int c = __hip_atomic_load(&rg->xcd_cnt[i], __ATOMIC_RELAXED, __HIP_MEMORY_SCOPE_AGENT);
                if (c > bestc) { bestc = c; best = i; }
            }
            dec = (bestc >= 32 && bestc <= 48) ? best : -1;
            u32 ep0 = (u32)((__builtin_amdgcn_s_memrealtime() >> 15) & 0x7fffu);
            __hip_atomic_store(&rg->epoch, ep0, __ATOMIC_RELAXED, __HIP_MEMORY_SCOPE_AGENT);
            __hip_atomic_store(&rg->decision, dec, __ATOMIC_RELAXED, __HIP_MEMORY_SCOPE_AGENT);
            __hip_atomic_store(&rg->ready, 1, __ATOMIC_RELEASE, __HIP_MEMORY_SCOPE_AGENT);
        } else {
            int it = 0;
            while (__hip_atomic_load(&rg->ready, __ATOMIC_ACQUIRE, __HIP_MEMORY_SCOPE_AGENT) == 0
                   && ++it < 4000000) __builtin_amdgcn_s_sleep(2);
            dec = __hip_atomic_load(&rg->decision, __ATOMIC_RELAXED, __HIP_MEMORY_SCOPE_AGENT);
        }
        u32 ep0 = __hip_atomic_load(&rg->epoch, __ATOMIC_RELAXED, __HIP_MEMORY_SCOPE_AGENT);
        int role = -1, lcv = 0;
        if (dec >= 0) { if (myxcd == dec && myIdx < 32) { role = myIdx; lcv = 1; } }
        else if (myArr < 32) role = myArr;   // fallback: first 32 arrivals, sc1 path

        if (lcv) {
            // Two-round canary, launch-unique values, using the EXACT read
            // mechanism of the main loop (plain load + acquire fence).
            // Round 1: sc0-store visibility + cross-launch staleness.
            // Round 2: repeated-address TIMELY update visibility (the R6
            // failure mode) -- tight budget converts "slow" into demote.
            u32* can = (u32*)((char*)ws + WS_CAN_OFF);
            const u32 K1 = (ep0 << 16) | 0x1A51u;
            const u32 K2 = (ep0 << 16) | 0xA515u;
            if (role == 0) {
                st_sc0(can, K1);
                asm volatile("s_waitcnt vmcnt(0)" ::: "memory");
                __hip_atomic_store(&rg->ready2, 1, __ATOMIC_RELEASE, __HIP_MEMORY_SCOPE_AGENT);
            }
            { int it = 0; while (__hip_atomic_load(&rg->ready2, __ATOMIC_ACQUIRE, __HIP_MEMORY_SCOPE_AGENT) == 0
                                 && ++it < 4000000) __builtin_amdgcn_s_sleep(2); }
            int ok1 = poll_exact_loc(can, K1);
            atomicAdd(&rg->votes1, ok1 ? 0x10000u : 0x10001u);
            if (role == 0) {
                int it = 0;
                while ((__hip_atomic_load(&rg->votes1, __ATOMIC_RELAXED, __HIP_MEMORY_SCOPE_AGENT) >> 16) < 32u
                       && ++it < 4000000) __builtin_amdgcn_s_sleep(2);
                st_sc0(can, K2);                       // SAME address, new value
                asm volatile("s_waitcnt vmcnt(0)" ::: "memory");
            }
            int ok2 = poll_exact_loc(can, K2);
            atomicAdd(&rg->votes2, ok2 ? 0x10000u : 0x10001u);
            if (role == 0) {
                int it = 0;
                while ((__hip_atomic_load(&rg->votes2, __ATOMIC_RELAXED, __HIP_MEMORY_SCOPE_AGENT) >> 16) < 32u
                       && ++it < 4000000) __builtin_amdgcn_s_sleep(2);
                u32 v1 = __hip_atomic_load(&rg->votes1, __ATOMIC_RELAXED, __HIP_MEMORY_SCOPE_AGENT);
                u32 v2 = __hip_atomic_load(&rg->votes2, __ATOMIC_RELAXED, __HIP_MEMORY_SCOPE_AGENT);
                int vd = (((v1 & 0xffffu) == 32u) && ((v2 & 0xffffu) == 32u)) ? 3 : 2;
                __hip_atomic_store(&rg->verdict, vd, __ATOMIC_RELEASE, __HIP_MEMORY_SCOPE_AGENT);
            }
            int vd = 0;
            { int it = 0; while ((((vd = __hip_atomic_load(&rg->verdict, __ATOMIC_ACQUIRE, __HIP_MEMORY_SCOPE_AGENT)) & 2) == 0)
                                 && ++it < 6000000) __builtin_amdgcn_s_sleep(2); }
            lcv = vd & 1;                              // single-writer verdict: all agree
        }
        ((volatile int*)lds)[0] = role;
        ((volatile int*)lds)[1] = lcv;
        ((volatile u32*)lds)[2] = ep0;
    }
    __syncthreads();
    const int wg = ((volatile int*)lds)[0];
    const int lc0 = ((volatile int*)lds)[1];
    const u32 ep = ((volatile u32*)lds)[2];
    __syncthreads();
    if (wg < 0) return;                          // 224 non-worker blocks exit
    const bool loc = (lc0 != 0);

    // region select: clustered region is ONLY ever touched by sc0/plain ops;
    // fallback region ONLY by sc1 ops (prevents stale-dirty-line crosstalk)
    u32* hx = (u32*)((char*)ws + (loc ? WS_HEXC_OFF : WS_HEXF_OFF));
    int* fl = (int*)((char*)ws + (loc ? WS_FLAGC_OFF : WS_FLAGF_OFF));

    const int layer = wg >> 4;
    const int g = wg & 15;
    const int ubase = g * UPW;

    // ---- dtype probe ----
    if (tid == 0) *(volatile int*)lds = 0;
    __syncthreads();
    {
        int e = (((const u16*)x)[(u32)tid * 64] >> 7) & 0xff;
        if (e >= 96 && e <= 144) atomicAdd((int*)lds, 1);
    }
    __syncthreads();
    const bool bfm = (*(volatile int*)lds >= 150);
    __syncthreads();

    const u16* Wih = layer ? Wih1 : Wih0;
    const u16* Whh = layer ? Whh1 : Whh0;
    const u16* bias = layer ? b1 : b0;

    // ---- load fused [W_ih | W_hh] slice into LDS ----
    if (tid == 0) *(volatile int*)(lds + OFF_DEAD) = 0;
    for (int c = tid; c < ROWS * 64; c += 256) {
        int r = c >> 6, part = c & 63;
        int R = (r & 3) * 256 + ubase + (r >> 2);    // gate*256 + unit
        uint4 v;
        if (bfm) {
            v = (part < 32) ? ((const uint4*)Wih)[R * 32 + part]
                            : ((const uint4*)Whh)[R * 32 + (part - 32)];
        } else {
            const uint4* s = (part < 32) ? ((const uint4*)Wih) + R * 64 + part * 2
                                         : ((const uint4*)Whh) + R * 64 + (part - 32) * 2;
            v = cvt8(s[0], s[1]);
        }
        *(uint4*)(lds + OFF_W + r * (KP * 2) + part * 16) = v;
    }

    // ---- per-thread recurrent state ----
    const int b = tid & 31;
    const int u0 = tid >> 5;            // 0..7
    const bool len64 = (lengths[1] == 0);
    const int lenb = len64 ? lengths[2 * b] : lengths[b];
    float cr[2], hp[2], bi[2][4];
#pragma unroll
    for (int pp = 0; pp < 2; ++pp) {
        int ug = ubase + u0 + 8 * pp;
        int idx = layer * BB * HH + b * HH + ug;
        cr[pp] = bfm ? bf2f(c0[idx]) : ((const float*)c0)[idx];
        hp[pp] = bfm ? bf2f(h0[idx]) : ((const float*)h0)[idx];
#pragma unroll
        for (int gate = 0; gate < 4; ++gate)
            bi[pp][gate] = bfm ? bf2f(bias[gate * 256 + ug])
                               : ((const float*)bias)[gate * 256 + ug];
    }

    // x prefetch (layer 0)
    uint4 xr[8];
    if (layer == 0) {
        if (bfm) {
#pragma unroll
            for (int j = 0; j < 4; ++j) xr[j] = ((const uint4*)x)[tid + j * 256];
        } else {
#pragma unroll
            for (int j = 0; j < 4; ++j) {
                int e = tid + j * 256;
                xr[2 * j]     = ((const uint4*)x)[2 * e];
                xr[2 * j + 1] = ((const uint4*)x)[2 * e + 1];
            }
        }
    }

    const int lane = tid & 63;
    const int wave = tid >> 6;
    const int lq = lane >> 4;
    const int lm = lane & 15;
    int blkdead = 0;     // block-wide poison: once set, never poll again

    __syncthreads();   // weights + dead flag visible

    for (int t = 0; t < TT; ++t) {
        const int slot = t & (NSLOT - 1);
        const int pslot = (t - 1) & (NSLOT - 1);

        // ---- producer waits (wave0) + ring back-pressure (wave1) ----
        if (!blkdead) {
            int to = 0;
            if (layer == 0) {
                if (wave == 0 && lane < 16 && t > 0) {
                    int* f = &fl[(0 * NSLOT + pslot) * NG + lane];
                    to = loc ? poll_flag_loc(f, ep, t) : poll_ge(f, t);
                }
                if (wave == 1 && lane < 16 && t >= NSLOT) {
                    int* f = &fl[(1 * NSLOT + slot) * NG + lane];
                    to = loc ? poll_flag_loc(f, ep, t - NSLOT + 1) : poll_ge(f, t - NSLOT + 1);
                }
            } else {
                if (wave == 0 && lane < 16) {
                    int* f = &fl[(0 * NSLOT + slot) * NG + lane];
                    to = loc ? poll_flag_loc(f, ep, t + 1) : poll_ge(f, t + 1);
                }
                if (wave == 1 && lane < 16 && t > 0) {
                    int* f = &fl[(1 * NSLOT + pslot) * NG + lane];
                    to = loc ? poll_flag_loc(f, ep, t) : poll_ge(f, t);
                }
            }
            if (to) atomicOr((int*)(lds + OFF_DEAD), 1);
        }
        asm volatile("" ::: "memory");
        __syncthreads();
        blkdead |= *(volatile int*)(lds + OFF_DEAD);

        // ---- stage hx_tile = [x_t or h0_t | h_prev] into LDS ----
        if (layer == 0) {
#pragma unroll
            for (int j = 0; j < 4; ++j) {
                int e = tid + j * 256;
                uint4 v = bfm ? xr[j] : cvt8(xr[2 * j], xr[2 * j + 1]);
                *(uint4*)(lds + OFF_HX + (e >> 5) * (KP * 2) + (e & 31) * 16) = v;
            }
            if (t == 0) {
#pragma unroll
                for (int j = 0; j < 16; ++j) {
                    int d = tid + j * 256;
                    u32 v = bfm ? ((const u32*)h0)[d]
                                : pack2(((const float*)h0)[2 * d], ((const float*)h0)[2 * d + 1]);
                    *(u32*)(lds + OFF_HX + (d >> 7) * (KP * 2) + 512 + (d & 127) * 4) = v;
                }
            } else {
                if (loc) {
                    // fresh-by-fence: L1 invalidated, uint4 loads hit local L2
                    inv_acq();
                    const uint4* s4 = (const uint4*)(hx + (0 * NSLOT + pslot) * (BB * 128));
#pragma unroll
                    for (int j = 0; j < 4; ++j) {
                        int e = tid + j * 256;          // uint4 index, 32 per row
                        uint4 v = s4[e];
                        *(uint4*)(lds + OFF_HX + (e >> 5) * (KP * 2) + 512 + (e & 31) * 16) = v;
                    }
                } else {
                    u32* src = hx + (0 * NSLOT + pslot) * (BB * 128);
#pragma unroll
                    for (int j = 0; j < 16; ++j) {
                        int d = tid + j * 256;
                        u32 v = cload(src + d);
                        *(u32*)(lds + OFF_HX + (d >> 7) * (KP * 2) + 512 + (d & 127) * 4) = v;
                    }
                }
            }
            if (t + 1 < TT) {
                if (bfm) {
#pragma unroll
                    for (int j = 0; j < 4; ++j)
                        xr[j] = ((const uint4*)x)[(t + 1) * 1024 + tid + j * 256];
                } else {
#pragma unroll
                    for (int j = 0; j < 4; ++j) {
                        int e = tid + j * 256;
                        xr[2 * j]     = ((const uint4*)x)[(t + 1) * 2048 + 2 * e];
                        xr[2 * j + 1] = ((const uint4*)x)[(t + 1) * 2048 + 2 * e + 1];
                    }
                }
            }
        } else {
            if (loc) {
                inv_acq();
                const uint4* s40 = (const uint4*)(hx + (0 * NSLOT + slot) * (BB * 128));
#pragma unroll
                for (int j = 0; j < 4; ++j) {          // K[0:256) = h0_t from layer 0
                    int e = tid + j * 256;
                    uint4 v = s40[e];
                    *(uint4*)(lds + OFF_HX + (e >> 5) * (KP * 2) + (e & 31) * 16) = v;
                }
                if (t > 0) {
                    const uint4* s41 = (const uint4*)(hx + (1 * NSLOT + pslot) * (BB * 128));
#pragma unroll
                    for (int j = 0; j < 4; ++j) {
                        int e = tid + j * 256;
                        uint4 v = s41[e];
                        *(uint4*)(lds + OFF_HX + (e >> 5) * (KP * 2) + 512 + (e & 31) * 16) = v;
                    }
                } else {
#pragma unroll
                    for (int j = 0; j < 16; ++j) {
                        int d = tid + j * 256;
                        u32 v = bfm ? ((const u32*)h0)[4096 + d]
                                    : pack2(((const float*)h0)[8192 + 2 * d],
                                            ((const float*)h0)[8192 + 2 * d + 1]);
                        *(u32*)(lds + OFF_HX + (d >> 7) * (KP * 2) + 512 + (d & 127) * 4) = v;
                    }
                }
            } else {
                u32* src0 = hx + (0 * NSLOT + slot) * (BB * 128);
#pragma unroll
                for (int j = 0; j < 16; ++j) {
                    int d = tid + j * 256;
                    u32 v = cload(src0 + d);
                    *(u32*)(lds + OFF_HX + (d >> 7) * (KP * 2) + (d & 127) * 4) = v;
                }
                if (t == 0) {
#pragma unroll
                    for (int j = 0; j < 16; ++j) {
                        int d = tid + j * 256;
                        u32 v = bfm ? ((const u32*)h0)[4096 + d]
                                    : pack2(((const float*)h0)[8192 + 2 * d],
                                            ((const float*)h0)[8192 + 2 * d + 1]);
                        *(u32*)(lds + OFF_HX + (d >> 7) * (KP * 2) + 512 + (d & 127) * 4) = v;
                    }
                } else {
                    u32* src1 = hx + (1 * NSLOT + pslot) * (BB * 128);
#pragma unroll
                    for (int j = 0; j < 16; ++j) {
                        int d = tid + j * 256;
                        u32 v = cload(src1 + d);
                        *(u32*)(lds + OFF_HX + (d >> 7) * (KP * 2) + 512 + (d & 127) * 4) = v;
                    }
                }
            }
        }
        __syncthreads();

        // ---- MFMA: gates[batch 32][row 64] = hx[32,512] @ W[64,512]^T ----
        {
            f32x4 acc0 = {0.f, 0.f, 0.f, 0.f}, acc1 = {0.f, 0.f, 0.f, 0.f};
            const int n = wave * 16 + lm;
            const char* wrow  = lds + OFF_W  + n * (KP * 2) + lq * 16;
            const char* arow0 = lds + OFF_HX + lm * (KP * 2) + lq * 16;
            const char* arow1 = lds + OFF_HX + (16 + lm) * (KP * 2) + lq * 16;
#pragma unroll
            for (int ks = 0; ks < 16; ++ks) {
                bf16x8 bf = *(const bf16x8*)(wrow + ks * 64);
                bf16x8 a0 = *(const bf16x8*)(arow0 + ks * 64);
                bf16x8 a1 = *(const bf16x8*)(arow1 + ks * 64);
                acc0 = __builtin_amdgcn_mfma_f32_16x16x32_bf16(a0, bf, acc0, 0, 0, 0);
                acc1 = __builtin_amdgcn_mfma_f32_16x16x32_bf16(a1, bf, acc1, 0, 0, 0);
            }
            float* gcol = (float*)(lds + OFF_G) + n * 33;   // gates[row][batch]
#pragma unroll
            for (int r = 0; r < 4; ++r) {
                gcol[lq * 4 + r]      = acc0[r];
                gcol[16 + lq * 4 + r] = acc1[r];
            }
        }
        __syncthreads();

        // ---- pointwise LSTM cell update (fp32) ----
        {
            const float* gb = (const float*)(lds + OFF_G);
            u16* hob = (u16*)(lds + OFF_HOB);
            u16* cob = (u16*)(lds + OFF_COB);
#pragma unroll
            for (int pp = 0; pp < 2; ++pp) {
                int u = u0 + 8 * pp;
                float gi = gb[(4 * u + 0) * 33 + b] + bi[pp][0];
                float gf = gb[(4 * u + 1) * 33 + b] + bi[pp][1];
                float gg = gb[(4 * u + 2) * 33 + b] + bi[pp][2];
                float go = gb[(4 * u + 3) * 33 + b] + bi[pp][3];
                float si = 1.f / (1.f + __expf(-gi));
                float sf = 1.f / (1.f + __expf(-gf));
                float so = 1.f / (1.f + __expf(-go));
                float cn = sf * cr[pp] + si * tanhf(gg);
                float hn = so * tanhf(cn);
                if (t >= lenb) { cn = cr[pp]; hn = hp[pp]; }
                cr[pp] = cn; hp[pp] = hn;
                hob[b * UPW + u] = f2bf(hn);
                cob[b * UPW + u] = f2bf(cn);
                if (!bfm) {
                    ((float*)(lds + OFF_HOF))[b * UPW + u] = hn;
                    ((float*)(lds + OFF_COF))[b * UPW + u] = cn;
                }
            }
        }
        __syncthreads();

        // ---- publish h slice; flag; THEN layer-1 hs/cs output writes ----
        const u32 hv = ((const u32*)(lds + OFF_HOB))[tid];
        const int bb2 = tid >> 3, u2 = tid & 7;
        {
            u32* dst = hx + (layer * NSLOT + slot) * (BB * 128) + bb2 * 128 + g * 8 + u2;
            if (loc) st_sc0(dst, hv); else cstore(dst, hv);
        }
        asm volatile("s_waitcnt vmcnt(0)" ::: "memory");
        __syncthreads();
        if (tid == 0) {
            int* f = &fl[(layer * NSLOT + slot) * NG + g];
            if (loc) st_sc0((u32*)f, (ep << 16) | (u32)(t + 1));
            else __hip_atomic_store(f, t + 1, __ATOMIC_RELAXED, __HIP_MEMORY_SCOPE_AGENT);
        }
        if (layer == 1) {
            if (bfm) {
                u32 cv = ((const u32*)(lds + OFF_COB))[tid];
                u32* outu = (u32*)out;
                outu[t * 4096 + bb2 * 128 + g * 8 + u2] = hv;
                outu[(TT * BB * HH / 2) + t * 4096 + bb2 * 128 + g * 8 + u2] = cv;
            } else {
                float2 h2 = ((const float2*)(lds + OFF_HOF))[tid];
                float2 c2 = ((const float2*)(lds + OFF_COF))[tid];
                float2* outf2 = (float2*)out;
                outf2[t * 4096 + bb2 * 128 + g * 8 + u2] = h2;
                outf2[(TT * BB * HH / 2) + t * 4096 + bb2 * 128 + g * 8 + u2] = c2;
            }
        }
        __syncthreads();
    }

    // ---- finals: h_T, c_T (post-mask, held in regs) ----
    {
        const int base = 2 * TT * BB * HH;
#pragma unroll
        for (int pp = 0; pp < 2; ++pp) {
            int ug = ubase + u0 + 8 * pp;
            if (bfm) {
                out[base + layer * BB * HH + b * HH + ug] = f2bf(hp[pp]);
                out[base + 2 * BB * HH + layer * BB * HH + b * HH + ug] = f2bf(cr[pp]);
            } else {
                float* outf = (float*)out;
                outf[base + layer * BB * HH + b * HH + ug] = hp[pp];
                outf[base + 2 * BB * HH + layer * BB * HH + b * HH + ug] = cr[pp];
            }
        }
    }
}

extern "C" void kernel_launch(void* const* d_in, const int* in_sizes, int n_in,
                              void* d_out, int out_size, void* d_ws, size_t ws_size,
                              hipStream_t stream) {
    (void)in_sizes; (void)n_in; (void)out_size; (void)ws_size;
    // Deterministic init of FALLBACK region + ClusterReg only. The clustered
    // region needs NO init: epoch-tagged exact-match flags make any initial
    // (or stale) memory content a non-match, and h_ex reads are gated by
    // this launch's flags.
    hipMemsetAsync(d_ws, 0, WS_FLAGF_OFF, stream);
    hipMemsetAsync((char*)d_ws + WS_FLAGF_OFF, 0xFF, WS_FLAG_BYTES, stream);
    hipMemsetAsync((char*)d_ws + WS_REG_OFF, 0, WS_REG_BYTES, stream);
    hipFuncSetAttribute((const void*)lstm_kernel,
                        hipFuncAttributeMaxDynamicSharedMemorySize, LDS_BYTES);
    lstm_kernel<<<dim3(NBLK), dim3(256), LDS_BYTES, stream>>>(
        (const u16*)d_in[0], (const int*)d_in[1],
        (const u16*)d_in[2], (const u16*)d_in[3],
        (const u16*)d_in[4], (const u16*)d_in[5], (const u16*)d_in[6],
        (const u16*)d_in[7], (const u16*)d_in[8], (const u16*)d_in[9],
        (u16*)d_out, (u32*)d_ws);
}